// Round 1
// baseline (753.392 us; speedup 1.0000x reference)
//
#include <hip/hip_runtime.h>

typedef unsigned long long u64;
typedef __attribute__((ext_vector_type(8))) short short8;
typedef __attribute__((ext_vector_type(4))) float f32x4;

#define NB 8
#define PP 65536
#define CC 21
#define LOC_PER_B 16384   // H*W
#define EMB_SCALE_F 9.76762622f
#define NID 1000

// ---- workspace layout (bytes) ----
#define OFF_KEYS   0ull                    // u64[8*65536]      = 4 MB
#define OFF_HIST   4194304ull              // u32[8*65536]      = 2 MB
#define OFF_WBF    6291456ull              // bf16[1000*256]    = 512000 B
#define OFF_NUMPOS 6803456ull              // int[8]
#define OFF_PREFIX 6803488ull              // u64[8]
#define OFF_KREM   6803552ull              // u32[8]
#define OFF_DONE   6803584ull              // u32[8]
#define OFF_ACCUM  6803616ull              // float[2]
// zero-init tail region: OFF_NUMPOS .. OFF_ACCUM+8 = 168 B = 42 u32

__device__ __forceinline__ unsigned short f2bf(float f) {
    unsigned u = __float_as_uint(f);
    u = (u + 0x7FFFu + ((u >> 16) & 1u)) >> 16;   // RNE
    return (unsigned short)u;
}

// ---------------- init: zero hist + small state tail ----------------
__global__ void k_init(unsigned* __restrict__ hist, unsigned* __restrict__ tail) {
    int idx = blockIdx.x * 256 + threadIdx.x;
    if (idx < 524288) hist[idx] = 0u;
    int t = idx - 524288;
    if (t >= 0 && t < 42) tail[t] = 0u;
}

// ---------------- pre-convert W to bf16 ----------------
__global__ void k_wprep(const float* __restrict__ Wm, unsigned short* __restrict__ wbf) {
    int idx = blockIdx.x * 256 + threadIdx.x;    // float4 index, 64000 total
    if (idx >= 64000) return;
    float4 v = ((const float4*)Wm)[idx];
    ushort4 h;
    h.x = f2bf(v.x); h.y = f2bf(v.y); h.z = f2bf(v.z); h.w = f2bf(v.w);
    ((ushort4*)wbf)[idx] = h;
}

// ---------------- bg_loss -> composite keys + positive count ----------------
__global__ void k_keys(const float* __restrict__ conf, const int* __restrict__ labels,
                       u64* __restrict__ keys, int* __restrict__ numPos) {
    int idx = blockIdx.x * 256 + threadIdx.x;    // 524288
    int b = idx >> 16;
    int p = idx & 65535;
    const float* c = conf + (size_t)idx * CC;
    float x0 = c[0];
    float m = x0;
#pragma unroll
    for (int j = 1; j < CC; ++j) m = fmaxf(m, c[j]);
    float s = 0.f;
#pragma unroll
    for (int j = 0; j < CC; ++j) s += __expf(c[j] - m);
    float bg = m + __logf(s) - x0;               // -log_softmax[0] >= 0
    bool pos = labels[idx] > 0;
    unsigned u = __float_as_uint(bg);
    u = (u & 0x80000000u) ? ~u : (u | 0x80000000u);   // ascending sortable
    u64 key = pos ? 0ull : ((((u64)u) << 32) | (u64)(0xFFFFFFFFu - (unsigned)p));
    keys[idx] = key;
    u64 bal = __ballot(pos);
    if ((threadIdx.x & 63) == 0) {
        int cnt = __popcll(bal);
        if (cnt) atomicAdd(&numPos[b], cnt);
    }
}

// ---------------- init radix-select state ----------------
__global__ void k_state(const int* __restrict__ numPos, u64* __restrict__ prefix,
                        unsigned* __restrict__ kRem, unsigned* __restrict__ done) {
    int b = threadIdx.x;
    if (b < NB) {
        long long np = numPos[b];
        long long k = np * 15;
        long long neg = PP - np;
        if (k > neg) k = neg;
        prefix[b] = 0ull;
        kRem[b] = (unsigned)k;
        done[b] = (k == 0) ? 1u : 0u;
    }
}

// ---------------- radix select: histogram pass ----------------
template<int PASS>
__global__ void k_hist(const u64* __restrict__ keys, const u64* __restrict__ prefix,
                       const unsigned* __restrict__ done, unsigned* __restrict__ hist) {
    int idx = blockIdx.x * 256 + threadIdx.x;
    int b = idx >> 16;
    if (done[b]) return;
    u64 key = keys[idx];
    if (PASS > 0) {
        const int hs = 64 - 16 * PASS;
        if ((key >> hs) != (prefix[b] >> hs)) return;
    }
    unsigned digit = (unsigned)((key >> (48 - 16 * PASS)) & 0xFFFFull);
    atomicAdd(&hist[(b << 16) + (int)digit], 1u);
}

// ---------------- radix select: scan pass (+zero hist) ----------------
template<int PASS>
__global__ void k_scan(u64* __restrict__ prefix, unsigned* __restrict__ kRem,
                       const unsigned* __restrict__ done, unsigned* __restrict__ hist) {
    int b = blockIdx.x;
    int tid = threadIdx.x;
    __shared__ unsigned chunkSum[256];
    unsigned* h = hist + (b << 16);
    if (!done[b]) {
        unsigned s = 0;
        int base = tid << 8;
        for (int i = 0; i < 256; ++i) s += h[base + i];
        chunkSum[tid] = s;
        __syncthreads();
        if (tid == 0) {
            unsigned k = kRem[b];
            u64 cum = 0;
            int c = 0;
            for (int i = 255; i >= 0; --i) {
                unsigned cs = chunkSum[i];
                if (cum + cs >= (u64)k) { c = i; break; }
                cum += cs;
            }
            int d = 0;
            for (int i = 255; i >= 0; --i) {
                unsigned hh = h[(c << 8) + i];
                if (cum + hh >= (u64)k) { d = i; break; }
                cum += hh;
            }
            unsigned digit = (unsigned)((c << 8) + d);
            kRem[b] = k - (unsigned)cum;
            prefix[b] |= ((u64)digit) << (48 - 16 * PASS);
        }
        __syncthreads();
    }
    for (int i = 0; i < 256; ++i) h[(i << 8) + tid] = 0u;   // ready for next pass
}

// ---------------- fused normalize + GEMM(MFMA) + logsumexp CE ----------------
__launch_bounds__(256, 2)
__global__ void k_ce(const float* __restrict__ pid, const int* __restrict__ labels,
                     const int* __restrict__ gt, const unsigned short* __restrict__ wbf,
                     const float* __restrict__ bias, const u64* __restrict__ keys,
                     const u64* __restrict__ prefix, const unsigned* __restrict__ done,
                     float* __restrict__ accum) {
    __shared__ __align__(16) char Xs[32768];   // 64 rows x 512B bf16, swizzled
    __shared__ __align__(16) char Ws[32768];   // 64 rows x 512B bf16, swizzled
    // metadata overlays Xs after A-fragments are in registers
    int*      gid_s  = (int*)Xs;
    unsigned* mask_s = (unsigned*)(Xs + 256);
    float*    fsum   = (float*)(Xs + 512);
    float*    fgl    = (float*)(Xs + 768);

    int tid = threadIdx.x;
    int blk = blockIdx.x;            // 2048
    int b = blk >> 8;
    int locBase = (blk & 255) << 6;
    size_t gLoc = (size_t)b * LOC_PER_B + (size_t)locBase;

    int wv = tid >> 6, lane = tid & 63;

    // --- stage X: normalize fp32 -> scale -> bf16, swizzled (one row per wave per iter)
    const float4* Xg = (const float4*)pid + gLoc * 64;
    for (int it = 0; it < 16; ++it) {
        int r = (it << 2) + wv;
        float4 v = Xg[(size_t)r * 64 + lane];
        float ss = v.x * v.x + v.y * v.y + v.z * v.z + v.w * v.w;
#pragma unroll
        for (int o = 32; o >= 1; o >>= 1) ss += __shfl_xor(ss, o, 64);
        float sc = EMB_SCALE_F / fmaxf(sqrtf(ss), 1e-12f);
        ushort4 h;
        h.x = f2bf(v.x * sc); h.y = f2bf(v.y * sc);
        h.z = f2bf(v.z * sc); h.w = f2bf(v.w * sc);
        int cb = lane << 3;
        *(ushort4*)(Xs + r * 512 + (cb ^ ((r & 7) << 4))) = h;
    }
    __syncthreads();

    // --- preload A fragments for this wave's 32 rows, full K=256 (held across N loop)
    int wrow = (wv >> 1) << 5;
    int wcol = (wv & 1) << 5;
    short8 afrag[2][8];
#pragma unroll
    for (int ci = 0; ci < 2; ++ci) {
        int r = wrow + (ci << 4) + (lane & 15);
        int swz = (r & 7) << 4;
#pragma unroll
        for (int ks = 0; ks < 8; ++ks) {
            int cb = (ks << 6) + ((lane >> 4) << 4);
            afrag[ci][ks] = *(const short8*)(Xs + r * 512 + (cb ^ swz));
        }
    }
    __syncthreads();   // all waves done reading Xs; safe to overlay metadata

    if (tid < 64) {
        int hw = locBase + tid;
        size_t pb = (size_t)b * PP + (size_t)hw * 4;
        int g0 = gt[pb], g1 = gt[pb + 1], g2 = gt[pb + 2], g3 = gt[pb + 3];
        int gid = max(max(g0, g1), max(g2, g3));
        u64 kth = prefix[b];
        unsigned dn = done[b];
        unsigned msk = 0;
#pragma unroll
        for (int a = 0; a < 4; ++a) {
            bool sel = (labels[pb + a] > 0) || (!dn && keys[pb + a] >= kth);
            if (sel) msk = 1u;
        }
        if (gid < 0) msk = 0;
        gid_s[tid] = gid;
        mask_s[tid] = msk;
        fsum[tid] = 0.f;
        fgl[tid] = 0.f;
    }

    float runsum[8], runl[8];
#pragma unroll
    for (int i = 0; i < 8; ++i) { runsum[i] = 0.f; runl[i] = 0.f; }

    const ushort4* Wt = (const ushort4*)wbf;   // [1000][64] ushort4
    for (int nt = 0; nt < 16; ++nt) {
        int n0 = nt << 6;
        __syncthreads();   // prev tile consumed (and metadata visible at nt=0)
        for (int it = 0; it < 16; ++it) {
            int g = (it << 8) + tid;
            int r = g >> 6, c4 = g & 63;
            int cls = n0 + r;
            ushort4 h;
            if (cls < NID) h = Wt[(size_t)cls * 64 + c4];
            else { h.x = 0; h.y = 0; h.z = 0; h.w = 0; }
            int cb = c4 << 3;
            *(ushort4*)(Ws + r * 512 + (cb ^ ((r & 7) << 4))) = h;
        }
        __syncthreads();

        f32x4 acc00 = {0.f,0.f,0.f,0.f}, acc01 = {0.f,0.f,0.f,0.f};
        f32x4 acc10 = {0.f,0.f,0.f,0.f}, acc11 = {0.f,0.f,0.f,0.f};
        int rc0 = wcol + (lane & 15);
        int rc1 = rc0 + 16;
        int swz0 = (rc0 & 7) << 4;   // (rc1 & 7) == (rc0 & 7)
        int kb = (lane >> 4) << 4;
#pragma unroll
        for (int ks = 0; ks < 8; ++ks) {
            int cb = (ks << 6) + kb;
            short8 b0 = *(const short8*)(Ws + rc0 * 512 + (cb ^ swz0));
            short8 b1 = *(const short8*)(Ws + rc1 * 512 + (cb ^ swz0));
            acc00 = __builtin_amdgcn_mfma_f32_16x16x32_bf16(afrag[0][ks], b0, acc00, 0, 0, 0);
            acc01 = __builtin_amdgcn_mfma_f32_16x16x32_bf16(afrag[0][ks], b1, acc01, 0, 0, 0);
            acc10 = __builtin_amdgcn_mfma_f32_16x16x32_bf16(afrag[1][ks], b0, acc10, 0, 0, 0);
            acc11 = __builtin_amdgcn_mfma_f32_16x16x32_bf16(afrag[1][ks], b1, acc11, 0, 0, 0);
        }
        // epilogue: logits tiny -> sum exp directly (no max subtraction)
#pragma unroll
        for (int cj = 0; cj < 2; ++cj) {
            int cls = n0 + wcol + (cj << 4) + (lane & 15);
            if (cls < NID) {
                float bv = bias[cls];
                f32x4 a0 = cj ? acc01 : acc00;
                f32x4 a1 = cj ? acc11 : acc10;
#pragma unroll
                for (int reg = 0; reg < 4; ++reg) {
                    int r0 = wrow + ((lane >> 4) << 2) + reg;
                    float l0 = a0[reg] + bv;
                    runsum[reg] += __expf(l0);
                    if (cls == gid_s[r0]) runl[reg] += l0;
                    int r1 = r0 + 16;
                    float l1 = a1[reg] + bv;
                    runsum[4 + reg] += __expf(l1);
                    if (cls == gid_s[r1]) runl[4 + reg] += l1;
                }
            }
        }
    }

    // reduce across the 16 lanes of each column group
#pragma unroll
    for (int o = 1; o <= 8; o <<= 1) {
#pragma unroll
        for (int i = 0; i < 8; ++i) {
            runsum[i] += __shfl_xor(runsum[i], o, 64);
            runl[i]   += __shfl_xor(runl[i], o, 64);
        }
    }
    if ((lane & 15) == 0) {
        int rbase = wrow + ((lane >> 4) << 2);
#pragma unroll
        for (int reg = 0; reg < 4; ++reg) {
            atomicAdd(&fsum[rbase + reg],      runsum[reg]);
            atomicAdd(&fgl [rbase + reg],      runl[reg]);
            atomicAdd(&fsum[rbase + 16 + reg], runsum[4 + reg]);
            atomicAdd(&fgl [rbase + 16 + reg], runl[4 + reg]);
        }
    }
    __syncthreads();

    if (tid < 64) {
        float ce = __logf(fsum[tid]) - fgl[tid];
        float mm = (float)mask_s[tid];
        float cs = ce * mm;
#pragma unroll
        for (int o = 1; o <= 32; o <<= 1) {
            cs += __shfl_xor(cs, o, 64);
            mm += __shfl_xor(mm, o, 64);
        }
        if (tid == 0) {
            atomicAdd(&accum[0], cs);
            atomicAdd(&accum[1], mm);
        }
    }
}

__global__ void k_fin(const float* __restrict__ accum, float* __restrict__ out) {
    out[0] = accum[0] / fmaxf(accum[1], 1.0f);
}

extern "C" void kernel_launch(void* const* d_in, const int* in_sizes, int n_in,
                              void* d_out, int out_size, void* d_ws, size_t ws_size,
                              hipStream_t stream) {
    (void)in_sizes; (void)n_in; (void)out_size; (void)ws_size;
    const float* conf   = (const float*)d_in[0];
    const float* pid    = (const float*)d_in[1];
    const int*   labels = (const int*)d_in[2];
    const int*   gt     = (const int*)d_in[3];
    const float* Wm     = (const float*)d_in[4];
    const float* bias   = (const float*)d_in[5];
    float* out = (float*)d_out;
    char* ws = (char*)d_ws;

    u64* keys            = (u64*)(ws + OFF_KEYS);
    unsigned* hist       = (unsigned*)(ws + OFF_HIST);
    unsigned short* wbf  = (unsigned short*)(ws + OFF_WBF);
    int* numPos          = (int*)(ws + OFF_NUMPOS);
    u64* prefix          = (u64*)(ws + OFF_PREFIX);
    unsigned* kRem       = (unsigned*)(ws + OFF_KREM);
    unsigned* done       = (unsigned*)(ws + OFF_DONE);
    float* accum         = (float*)(ws + OFF_ACCUM);

    k_init <<<2049, 256, 0, stream>>>(hist, (unsigned*)(ws + OFF_NUMPOS));
    k_wprep<<<250,  256, 0, stream>>>(Wm, wbf);
    k_keys <<<2048, 256, 0, stream>>>(conf, labels, keys, numPos);
    k_state<<<1,    64,  0, stream>>>(numPos, prefix, kRem, done);

    k_hist<0><<<2048, 256, 0, stream>>>(keys, prefix, done, hist);
    k_scan<0><<<8,    256, 0, stream>>>(prefix, kRem, done, hist);
    k_hist<1><<<2048, 256, 0, stream>>>(keys, prefix, done, hist);
    k_scan<1><<<8,    256, 0, stream>>>(prefix, kRem, done, hist);
    k_hist<2><<<2048, 256, 0, stream>>>(keys, prefix, done, hist);
    k_scan<2><<<8,    256, 0, stream>>>(prefix, kRem, done, hist);
    k_hist<3><<<2048, 256, 0, stream>>>(keys, prefix, done, hist);
    k_scan<3><<<8,    256, 0, stream>>>(prefix, kRem, done, hist);

    k_ce <<<2048, 256, 0, stream>>>(pid, labels, gt, wbf, bias, keys, prefix, done, accum);
    k_fin<<<1, 1, 0, stream>>>(accum, out);
}

// Round 2
// 481.392 us; speedup vs baseline: 1.5650x; 1.5650x over previous
//
#include <hip/hip_runtime.h>

typedef unsigned long long u64;
typedef __attribute__((ext_vector_type(8))) short short8;
typedef __attribute__((ext_vector_type(4))) float f32x4;

#define NB 8
#define PP 65536
#define CC 21
#define LOC_PER_B 16384
#define EMB_SCALE_F 9.76762622f
#define NID 1000

// ---- workspace layout (bytes) ----
#define OFF_KEYS   0ull            // u64[8*65536]  = 4MB
#define OFF_HIST   4194304ull      // u32[8*65536]  = 2MB ; reused as cand u64[8][32768]
#define OFF_WSWZ   6291456ull      // bf16 pre-swizzled W tiles, 512KB
#define OFF_STATE  6815744ull      // small state block
// state offsets (bytes)
#define ST_NUMPOS   0    // int[8]
#define ST_CANDCNT  32   // u32[8]
#define ST_KTHHI    64   // u32[8]
#define ST_KREM     96   // u32[8]
#define ST_DONE     128  // u32[8]
#define ST_KTH      160  // u64[8]
#define ST_ACCUM    224  // float[2]
#define ST_WORDS    58

__device__ __forceinline__ unsigned short f2bf(float f) {
    unsigned u = __float_as_uint(f);
    u = (u + 0x7FFFu + ((u >> 16) & 1u)) >> 16;   // RNE
    return (unsigned short)u;
}

__device__ __forceinline__ void gl_lds16(const void* g, void* l) {
    __builtin_amdgcn_global_load_lds((const __attribute__((address_space(1))) unsigned*)g,
                                     (__attribute__((address_space(3))) unsigned*)l, 16, 0, 0);
}

// ---------------- init: zero hist + state ----------------
__global__ void k_init(unsigned* __restrict__ hist, unsigned* __restrict__ state) {
    int idx = blockIdx.x * 256 + threadIdx.x;
    if (idx < 524288) hist[idx] = 0u;
    int t = idx - 524288;
    if (t >= 0 && t < ST_WORDS) state[t] = 0u;
}

// ---------------- W -> pre-swizzled bf16 tile images ----------------
// image byte (tile, row, x): holds W[tile*64+row][(x ^ ((row&7)<<4))/2 ...]
__global__ void k_wprep(const float* __restrict__ Wm, unsigned short* __restrict__ wswz) {
    int g = blockIdx.x * 256 + threadIdx.x;    // 16B granule, 32768 total
    if (g >= 32768) return;
    int c    = g & 31;
    int row  = (g >> 5) & 63;
    int tile = g >> 11;
    int cls  = tile * 64 + row;
    int srcByte = (c << 4) ^ ((row & 7) << 4);
    ushort4 h0, h1;
    if (cls < NID) {
        const float* src = Wm + (size_t)cls * 256 + (srcByte >> 1);
        float4 a = *(const float4*)(src);
        float4 b = *(const float4*)(src + 4);
        h0.x = f2bf(a.x); h0.y = f2bf(a.y); h0.z = f2bf(a.z); h0.w = f2bf(a.w);
        h1.x = f2bf(b.x); h1.y = f2bf(b.y); h1.z = f2bf(b.z); h1.w = f2bf(b.w);
    } else {
        h0.x = h0.y = h0.z = h0.w = 0;
        h1.x = h1.y = h1.z = h1.w = 0;
    }
    ushort4* dst = (ushort4*)((char*)wswz + ((size_t)g << 4));
    dst[0] = h0; dst[1] = h1;
}

// ---------------- bg_loss -> keys + numPos + 16-bit histogram ----------------
__global__ void k_keys(const float* __restrict__ conf, const int* __restrict__ labels,
                       u64* __restrict__ keys, int* __restrict__ numPos,
                       unsigned* __restrict__ hist) {
    int idx = blockIdx.x * 256 + threadIdx.x;    // 524288
    int b = idx >> 16;
    int p = idx & 65535;
    const float* c = conf + (size_t)idx * CC;
    float x0 = c[0];
    float m = x0;
#pragma unroll
    for (int j = 1; j < CC; ++j) m = fmaxf(m, c[j]);
    float s = 0.f;
#pragma unroll
    for (int j = 0; j < CC; ++j) s += __expf(c[j] - m);
    float bg = m + __logf(s) - x0;
    bool pos = labels[idx] > 0;
    unsigned u = __float_as_uint(bg);
    u = (u & 0x80000000u) ? ~u : (u | 0x80000000u);
    u64 key = pos ? 0ull : ((((u64)u) << 32) | (u64)(0xFFFFFFFFu - (unsigned)p));
    keys[idx] = key;
    if (key) atomicAdd(&hist[(b << 16) + (int)(key >> 48)], 1u);
    u64 bal = __ballot(pos);
    if ((threadIdx.x & 63) == 0) {
        int cnt = __popcll(bal);
        if (cnt) atomicAdd(&numPos[b], cnt);
    }
}

// ---------------- parallel suffix-scan over 64K bins: pick top-16-bit digit ----------------
__global__ void k_scan0(const unsigned* __restrict__ hist, const int* __restrict__ numPos,
                        unsigned* __restrict__ kthHi, unsigned* __restrict__ kRem,
                        unsigned* __restrict__ done, u64* __restrict__ kth) {
    int b = blockIdx.x, t = threadIdx.x;   // 8 blocks x 1024
    __shared__ unsigned s[1024];
    __shared__ unsigned sh_c, sh_kk;
    int np = numPos[b];
    long long kk64 = (long long)np * 15;
    long long neg = (long long)PP - np;
    if (kk64 > neg) kk64 = neg;
    unsigned k = (unsigned)kk64;
    if (k == 0) { if (t == 0) { done[b] = 1u; kth[b] = ~0ull; } return; }
    const unsigned* h = hist + (b << 16);
    unsigned cs = 0;
    const uint4* hv = (const uint4*)(h + (t << 6));
#pragma unroll
    for (int j = 0; j < 16; ++j) { uint4 v = hv[j]; cs += v.x + v.y + v.z + v.w; }
    s[t] = cs; __syncthreads();
    for (int off = 1; off < 1024; off <<= 1) {
        unsigned v = (t + off < 1024) ? s[t + off] : 0u;
        __syncthreads(); s[t] += v; __syncthreads();
    }
    unsigned si = s[t];
    if (si >= k && si - cs < k) { sh_c = (unsigned)t; sh_kk = k - (si - cs); }
    __syncthreads();
    if (t < 64) {
        unsigned c = sh_c, kk = sh_kk;
        unsigned bin = h[(c << 6) + t];
        unsigned sfx = bin;
        for (int off = 1; off < 64; off <<= 1) {
            unsigned v = __shfl_down(sfx, off, 64);
            if (t + off < 64) sfx += v;
        }
        if (sfx >= kk && sfx - bin < kk) {
            kthHi[b] = (c << 6) | (unsigned)t;
            kRem[b]  = kk - (sfx - bin);
        }
    }
}

// ---------------- compact keys matching the selected top-16 digit ----------------
__global__ void k_compact(const u64* __restrict__ keys, const unsigned* __restrict__ kthHi,
                          const unsigned* __restrict__ done, u64* __restrict__ cand,
                          unsigned* __restrict__ candCnt) {
    int idx = blockIdx.x * 256 + threadIdx.x;
    int b = idx >> 16;
    if (done[b]) return;
    u64 key = keys[idx];
    if ((unsigned)(key >> 48) == kthHi[b]) {
        unsigned pos = atomicAdd(&candCnt[b], 1u);
        if (pos < 32768u) cand[((size_t)b << 15) + pos] = key;
    }
}

// ---------------- in-block radix over low 48 bits -> exact kth key ----------------
__global__ void k_select2(const u64* __restrict__ cand, const unsigned* __restrict__ candCnt,
                          const unsigned* __restrict__ kthHi, const unsigned* __restrict__ kRem,
                          const unsigned* __restrict__ done, u64* __restrict__ kth) {
    int b = blockIdx.x, t = threadIdx.x;   // 8 blocks x 256
    if (done[b]) return;
    __shared__ unsigned wh[4][256];
    __shared__ unsigned s[256];
    __shared__ u64 sh_pref;
    __shared__ unsigned sh_kk;
    int wv = t >> 6;
    unsigned n = candCnt[b]; if (n > 32768u) n = 32768u;
    if (t == 0) { sh_pref = 0ull; sh_kk = kRem[b]; }
    __syncthreads();
    const u64* cb = cand + ((size_t)b << 15);
    for (int pass = 0; pass < 6; ++pass) {
        int shift = 40 - 8 * pass;
        wh[0][t] = 0u; wh[1][t] = 0u; wh[2][t] = 0u; wh[3][t] = 0u;
        __syncthreads();
        u64 pref = sh_pref; unsigned kk = sh_kk;
        u64 himask = (~((1ull << (shift + 8)) - 1ull)) & 0x0000FFFFFFFFFFFFull;
        for (unsigned i = t; i < n; i += 256) {
            u64 kv = cb[i] & 0x0000FFFFFFFFFFFFull;
            if ((kv & himask) == pref)
                atomicAdd(&wh[wv][(unsigned)(kv >> shift) & 255u], 1u);
        }
        __syncthreads();
        unsigned hsum = wh[0][t] + wh[1][t] + wh[2][t] + wh[3][t];
        s[t] = hsum; __syncthreads();
        for (int off = 1; off < 256; off <<= 1) {
            unsigned v = (t + off < 256) ? s[t + off] : 0u;
            __syncthreads(); s[t] += v; __syncthreads();
        }
        unsigned si = s[t];
        if (si >= kk && si - hsum < kk) {
            sh_pref = pref | ((u64)t << shift);
            sh_kk = kk - (si - hsum);
        }
        __syncthreads();
    }
    if (t == 0) kth[b] = ((u64)kthHi[b] << 48) | sh_pref;
}

// ---------------- fused normalize + MFMA GEMM + logsumexp CE ----------------
// M=128/block, 2 panels, async double-buffered W staging via pre-swizzled source.
__launch_bounds__(256, 2)
__global__ void k_ce(const float* __restrict__ pid, const int* __restrict__ labels,
                     const int* __restrict__ gt, const unsigned short* __restrict__ wswz,
                     const float* __restrict__ bias, const u64* __restrict__ keys,
                     const u64* __restrict__ kth_, const unsigned* __restrict__ done_,
                     float* __restrict__ accum) {
    __shared__ __align__(16) char Ws[65536];      // X-stage image, then W double buffer
    __shared__ __align__(16) float biasLds[1024];
    __shared__ int gid_s[128];
    __shared__ unsigned mask_s[128];
    __shared__ float fsum[128];
    __shared__ float fgl[128];

    int tid = threadIdx.x;
    int blk = blockIdx.x;              // 1024
    int b = blk >> 7;
    int locBase = (blk & 127) << 7;    // 128 locations
    int wv = tid >> 6, lane = tid & 63;

    // ---- bias staging (pad >=1000 with -inf so exp()=0) ----
#pragma unroll
    for (int i = 0; i < 4; ++i) {
        int idx = tid + (i << 8);
        biasLds[idx] = (idx < NID) ? bias[idx] : -INFINITY;
    }

    // ---- stage X: normalize fp32 -> scale -> bf16, swizzled into Ws ----
    const float4* Xg = (const float4*)pid + ((size_t)b * LOC_PER_B + (size_t)locBase) * 64;
    for (int it = 0; it < 32; ++it) {
        int r = (it << 2) + wv;
        float4 v = Xg[(size_t)r * 64 + lane];
        float ss = v.x * v.x + v.y * v.y + v.z * v.z + v.w * v.w;
#pragma unroll
        for (int o = 32; o >= 1; o >>= 1) ss += __shfl_xor(ss, o, 64);
        float sc = EMB_SCALE_F / fmaxf(sqrtf(ss), 1e-12f);
        ushort4 h;
        h.x = f2bf(v.x * sc); h.y = f2bf(v.y * sc);
        h.z = f2bf(v.z * sc); h.w = f2bf(v.w * sc);
        *(ushort4*)(Ws + r * 512 + (((lane << 3)) ^ ((r & 7) << 4))) = h;
    }

    // ---- metadata ----
    if (tid < 128) {
        size_t pb = (size_t)b * PP + ((size_t)(locBase + tid) << 2);
        int g0 = gt[pb], g1 = gt[pb + 1], g2 = gt[pb + 2], g3 = gt[pb + 3];
        int gid = max(max(g0, g1), max(g2, g3));
        u64 kth = kth_[b];
        unsigned dn = done_[b];
        unsigned msk = 0;
#pragma unroll
        for (int a = 0; a < 4; ++a) {
            if (labels[pb + a] > 0 || (!dn && keys[pb + a] >= kth)) msk = 1u;
        }
        if (gid < 0) msk = 0;
        gid_s[tid] = min(max(gid, 0), NID - 1);
        mask_s[tid] = msk;
        fsum[tid] = 0.f;
        fgl[tid] = 0.f;
    }

    asm volatile("s_waitcnt lgkmcnt(0)" ::: "memory");
    asm volatile("s_barrier" ::: "memory");      // (A) X image + metadata visible

    // ---- preload A fragments: [panel][ci][ks], held across the whole N loop ----
    int wrow = (wv >> 1) << 5;     // 0 or 32 (within panel)
    int wcol = (wv & 1) << 5;      // 0 or 32 (within N tile)
    int kb = (lane >> 4) << 4;
    short8 af[2][2][8];
#pragma unroll
    for (int p = 0; p < 2; ++p)
#pragma unroll
        for (int ci = 0; ci < 2; ++ci) {
            int r = (p << 6) + wrow + (ci << 4) + (lane & 15);
            int swz = (r & 7) << 4;
#pragma unroll
            for (int ks = 0; ks < 8; ++ks)
                af[p][ci][ks] = *(const short8*)(Ws + r * 512 + ((((ks << 6) + kb)) ^ swz));
        }
    asm volatile("s_waitcnt lgkmcnt(0)" ::: "memory");
    asm volatile("s_barrier" ::: "memory");      // (B) all afrag reads done; Ws reusable

    // ---- issue W tiles 0,1 into double buffer ----
    const char* wg = (const char*)wswz;
    {
        const char* g0 = wg + (wv << 13) + (lane << 4);
        char* l0 = Ws + (wv << 13);
#pragma unroll
        for (int it = 0; it < 8; ++it) gl_lds16(g0 + (it << 10), l0 + (it << 10));
        const char* g1 = wg + 32768 + (wv << 13) + (lane << 4);
        char* l1 = Ws + 32768 + (wv << 13);
#pragma unroll
        for (int it = 0; it < 8; ++it) gl_lds16(g1 + (it << 10), l1 + (it << 10));
    }

    float runsum[16];
#pragma unroll
    for (int i = 0; i < 16; ++i) runsum[i] = 0.f;

    int rc0 = wcol + (lane & 15);
    int swzB = (rc0 & 7) << 4;
    int kbx = kb ^ (swzB & 48);
    int szh = swzB & 64;
    int rbase0 = rc0 * 512 + kbx;
    int rbase1 = (rc0 + 16) * 512 + kbx;

    for (int nt = 0; nt < 16; ++nt) {
        int p = nt & 1;
        if (nt < 15) asm volatile("s_waitcnt vmcnt(8)" ::: "memory");
        else         asm volatile("s_waitcnt vmcnt(0)" ::: "memory");
        asm volatile("s_barrier" ::: "memory");

        const char* Wp = Ws + (p << 15);
        f32x4 a00 = {0,0,0,0}, a01 = {0,0,0,0}, a10 = {0,0,0,0}, a11 = {0,0,0,0};
        f32x4 c00 = {0,0,0,0}, c01 = {0,0,0,0}, c10 = {0,0,0,0}, c11 = {0,0,0,0};
#pragma unroll
        for (int ks = 0; ks < 8; ++ks) {
            int o = ((ks << 6) ^ szh);
            short8 b0 = *(const short8*)(Wp + rbase0 + o);
            short8 b1 = *(const short8*)(Wp + rbase1 + o);
            a00 = __builtin_amdgcn_mfma_f32_16x16x32_bf16(af[0][0][ks], b0, a00, 0, 0, 0);
            a01 = __builtin_amdgcn_mfma_f32_16x16x32_bf16(af[0][0][ks], b1, a01, 0, 0, 0);
            a10 = __builtin_amdgcn_mfma_f32_16x16x32_bf16(af[0][1][ks], b0, a10, 0, 0, 0);
            a11 = __builtin_amdgcn_mfma_f32_16x16x32_bf16(af[0][1][ks], b1, a11, 0, 0, 0);
            c00 = __builtin_amdgcn_mfma_f32_16x16x32_bf16(af[1][0][ks], b0, c00, 0, 0, 0);
            c01 = __builtin_amdgcn_mfma_f32_16x16x32_bf16(af[1][0][ks], b1, c01, 0, 0, 0);
            c10 = __builtin_amdgcn_mfma_f32_16x16x32_bf16(af[1][1][ks], b0, c10, 0, 0, 0);
            c11 = __builtin_amdgcn_mfma_f32_16x16x32_bf16(af[1][1][ks], b1, c11, 0, 0, 0);
        }
        asm volatile("s_barrier" ::: "memory");   // all waves done reading buf p

        if (nt < 14) {
            const char* gs = wg + ((size_t)(nt + 2) << 15) + (wv << 13) + (lane << 4);
            char* ls = Ws + (p << 15) + (wv << 13);
#pragma unroll
            for (int it = 0; it < 8; ++it) gl_lds16(gs + (it << 10), ls + (it << 10));
        }

        // epilogue: sum exp(logit) only (gid-logit handled post-loop)
        int n0 = nt << 6;
        float bl0 = biasLds[n0 + wcol + (lane & 15)];
        float bl1 = biasLds[n0 + wcol + 16 + (lane & 15)];
#pragma unroll
        for (int reg = 0; reg < 4; ++reg) {
            runsum[reg]      += __expf(a00[reg] + bl0) + __expf(a01[reg] + bl1);
            runsum[4 + reg]  += __expf(a10[reg] + bl0) + __expf(a11[reg] + bl1);
            runsum[8 + reg]  += __expf(c00[reg] + bl0) + __expf(c01[reg] + bl1);
            runsum[12 + reg] += __expf(c10[reg] + bl0) + __expf(c11[reg] + bl1);
        }
    }

    // ---- gid-logit via register dot: rows p*64 + wrow + ci*16 + (lane&15) ----
    if ((wv & 1) == 0) {
#pragma unroll
        for (int p = 0; p < 2; ++p)
#pragma unroll
            for (int ci = 0; ci < 2; ++ci) {
                int r = (p << 6) + wrow + (ci << 4) + (lane & 15);
                int gid = gid_s[r];
                const char* wrp = (const char*)wswz + (size_t)gid * 512;
                int gswz = (gid & 7) << 4;
                float d = 0.f;
#pragma unroll
                for (int ks = 0; ks < 8; ++ks) {
                    short8 w8 = *(const short8*)(wrp + ((((ks << 6) + kb)) ^ gswz));
                    short8 a8 = af[p][ci][ks];
#pragma unroll
                    for (int j = 0; j < 8; ++j) {
                        float xa = __uint_as_float((unsigned)(unsigned short)a8[j] << 16);
                        float xw = __uint_as_float((unsigned)(unsigned short)w8[j] << 16);
                        d = fmaf(xa, xw, d);
                    }
                }
                d += __shfl_xor(d, 16, 64);
                d += __shfl_xor(d, 32, 64);
                if (lane < 16) fgl[r] = d + biasLds[gid];
            }
    }

    // ---- reduce runsum across the 16-lane column groups, merge into fsum ----
#pragma unroll
    for (int o = 1; o <= 8; o <<= 1)
#pragma unroll
        for (int i = 0; i < 16; ++i) runsum[i] += __shfl_xor(runsum[i], o, 64);

    if ((lane & 15) == 0) {
        int rb = wrow + ((lane >> 4) << 2);
#pragma unroll
        for (int p = 0; p < 2; ++p)
#pragma unroll
            for (int reg = 0; reg < 4; ++reg) {
                atomicAdd(&fsum[(p << 6) + rb + reg],      runsum[p * 8 + reg]);
                atomicAdd(&fsum[(p << 6) + rb + 16 + reg], runsum[p * 8 + 4 + reg]);
            }
    }
    __syncthreads();

    if (tid < 128) {
        float ce = __logf(fsum[tid]) - fgl[tid];
        float mm = (float)mask_s[tid];
        float cs = ce * mm;
#pragma unroll
        for (int o = 1; o <= 32; o <<= 1) {
            cs += __shfl_xor(cs, o, 64);
            mm += __shfl_xor(mm, o, 64);
        }
        if (lane == 0) {
            atomicAdd(&accum[0], cs);
            atomicAdd(&accum[1], mm);
        }
    }
}

__global__ void k_fin(const float* __restrict__ accum, float* __restrict__ out) {
    out[0] = accum[0] / fmaxf(accum[1], 1.0f);
}

extern "C" void kernel_launch(void* const* d_in, const int* in_sizes, int n_in,
                              void* d_out, int out_size, void* d_ws, size_t ws_size,
                              hipStream_t stream) {
    (void)in_sizes; (void)n_in; (void)out_size; (void)ws_size;
    const float* conf   = (const float*)d_in[0];
    const float* pid    = (const float*)d_in[1];
    const int*   labels = (const int*)d_in[2];
    const int*   gt     = (const int*)d_in[3];
    const float* Wm     = (const float*)d_in[4];
    const float* bias   = (const float*)d_in[5];
    float* out = (float*)d_out;
    char* ws = (char*)d_ws;

    u64* keys           = (u64*)(ws + OFF_KEYS);
    unsigned* hist      = (unsigned*)(ws + OFF_HIST);
    u64* cand           = (u64*)(ws + OFF_HIST);       // reuses hist region
    unsigned short* wsw = (unsigned short*)(ws + OFF_WSWZ);
    char* st            = ws + OFF_STATE;
    int* numPos         = (int*)(st + ST_NUMPOS);
    unsigned* candCnt   = (unsigned*)(st + ST_CANDCNT);
    unsigned* kthHi     = (unsigned*)(st + ST_KTHHI);
    unsigned* kRem      = (unsigned*)(st + ST_KREM);
    unsigned* done      = (unsigned*)(st + ST_DONE);
    u64* kth            = (u64*)(st + ST_KTH);
    float* accum        = (float*)(st + ST_ACCUM);

    k_init   <<<2049, 256, 0, stream>>>(hist, (unsigned*)st);
    k_wprep  <<<128,  256, 0, stream>>>(Wm, wsw);
    k_keys   <<<2048, 256, 0, stream>>>(conf, labels, keys, numPos, hist);
    k_scan0  <<<8,   1024, 0, stream>>>(hist, numPos, kthHi, kRem, done, kth);
    k_compact<<<2048, 256, 0, stream>>>(keys, kthHi, done, cand, candCnt);
    k_select2<<<8,    256, 0, stream>>>(cand, candCnt, kthHi, kRem, done, kth);
    k_ce     <<<1024, 256, 0, stream>>>(pid, labels, gt, wsw, bias, keys, kth, done, accum);
    k_fin    <<<1, 1, 0, stream>>>(accum, out);
}